// Round 8
// baseline (92.361 us; speedup 1.0000x reference)
//
#include <hip/hip_runtime.h>

// LogicConv3d: B=4, C=3, H=W=D=32, K=32, S=16 leaves, tree depth 4 (31 LUT nodes).
// Out: (B, K, 30, 30, 30) = 3,456,000 fp32.
//
// R18: od-per-lane scalar remap. Evidence: R11-R17 — pipe split, staging
// volume, barriers, SW pipelining, VGPR slack, 12->24 waves/CU ALL neutral at
// ~25us kernel; only added volume (R15) moves it (+20%). Remaining suspect:
// per-instruction address divergence. Every v8f/v4f B-gather instruction
// touches 16 ow-groups x distinct 128B d-rows = 16-32 unique cache lines ->
// TA serializes ~1 line/cyc -> ~10us hidden serial term that scales with
// NOTHING we varied. Fix: lane = od (half-wave = one (oh,ow) column):
//  - B-leaf: 1 global_load_dword, lanes consecutive -> EXACTLY 2 lines/instr
//    (d+od <= 31: never crosses a d-row)
//  - A-leaf: 1 conflict-free ds_read_b32 (stride-1 lanes; no padding needed)
//  - slab 3c x 3h x 32 x 32 dw = 36,864B -> 4 blocks/CU, 32 waves/CU (FULL)
//  - ~30 VGPR/thread via __launch_bounds__(512,8)
// Cost: ~2x instruction count per output (no v8f amortization) — the bet is
// that line-divergence, not issue, is the 25us floor.
// Kept: k-pair per block, A-LDS/B-global split, fused levels 0+1,
// softmax->delta LUT, bases via readfirstlane -> SGPR.

#define B_  4
#define C_  3
#define H_  32
#define W_  32
#define D_  32
#define K_  32
#define S_  16
#define TPB 512

__device__ __forceinline__ float lut1(float a, float b, float l0, float d1, float d2, float d3) {
    // E = l0 + a*d2 + b*d1 + (a*b)*d3 == fma(b, fma(a,d3,d1), fma(a,d2,l0))
    return fmaf(b, fmaf(a, d3, d1), fmaf(a, d2, l0));
}

__global__ __launch_bounds__(TPB, 8) void logic_conv3d(
    const float* __restrict__ x,
    const int*   __restrict__ kc,
    const float* __restrict__ w0,
    const float* __restrict__ w1,
    const float* __restrict__ w2,
    const float* __restrict__ w3,
    const float* __restrict__ w4,
    float*       __restrict__ out)
{
    __shared__ float4 s_lut[2][31];              // (l0, d1, d2, d3) per node, per kk
    __shared__ __align__(16) int s_lb[2][16];    // A-leaf base, slab dword coords, per kk
    __shared__ __align__(16) int s_gb[2][16];    // B-leaf base, global dword coords (b folded via ptr)
    __shared__ __align__(16) float slab[3 * 3 * 32 * 32];  // 9216 dwords = 36864 B

    const int bx  = blockIdx.x;      // b*16 + kp
    const int b   = bx >> 4;
    const int k0  = (bx & 15) << 1;  // first k of this block's pair
    const int tid = threadIdx.x;
    const int oh  = blockIdx.y;      // one oh row per block (0..29)

    // ---- per-block setup: 2 x (31 softmax->LUT delta form) + 2 x 32 leaf bases ----
    if (tid < 62) {
        const int kk   = (tid >= 31) ? 1 : 0;
        const int node = tid - kk * 31;
        const int k    = k0 + kk;
        const float* wp; int ln;
        if      (node < 16) { wp = w0; ln = node;      }
        else if (node < 24) { wp = w1; ln = node - 16; }
        else if (node < 28) { wp = w2; ln = node - 24; }
        else if (node < 30) { wp = w3; ln = node - 28; }
        else                { wp = w4; ln = 0;         }
        const float* wrow = wp + (ln * K_ + k) * 16;
        float lg[16];
        float m = -1e30f;
        #pragma unroll
        for (int g = 0; g < 16; ++g) { lg[g] = wrow[g]; m = fmaxf(m, lg[g]); }
        float z = 0.f;
        #pragma unroll
        for (int g = 0; g < 16; ++g) { lg[g] = __expf(lg[g] - m); z += lg[g]; }
        const float inv = 1.0f / z;
        float l0 = 0.f, l1 = 0.f, l2 = 0.f, l3 = 0.f;
        #pragma unroll
        for (int g = 0; g < 16; ++g) {
            float p = lg[g] * inv;           // GATES[g,t] = (g>>t)&1, t = 2*a+b
            if (g & 1) l0 += p;
            if (g & 2) l1 += p;
            if (g & 4) l2 += p;
            if (g & 8) l3 += p;
        }
        s_lut[kk][node] = make_float4(l0, l1 - l0, l2 - l0, (l3 - l2) - (l1 - l0));
    } else if (tid >= 64 && tid < 128) {
        const int idx  = tid - 64;           // kk*32 + tree*16 + s
        const int kk   = idx >> 5;
        const int tree = (idx >> 4) & 1;
        const int s    = idx & 15;
        const int k    = k0 + kk;
        const int off  = ((tree * K_ + k) * S_ + s) * 4;  // kc (2,K,S,4) = (h,w,d,c)
        const int h = kc[off + 0], w = kc[off + 1], d = kc[off + 2], c = kc[off + 3];
        if (tree == 0)
            s_lb[kk][s] = ((c * 3 + h) * 32 + w) * 32 + d;            // slab dwords
        else
            s_gb[kk][s] = ((c * H_ + (oh + h)) * W_ + w) * D_ + d;    // global dwords (oh folded)
    }

    const float* xg = x + (size_t)b * (C_ * H_ * W_ * D_);

    // ---- stage slab: 9 planes (3c x 3h) of 32x32 dwords, coalesced float4 ----
    {
        #pragma unroll
        for (int it = 0; it < 5; ++it) {
            const int idx = it * TPB + tid;     // float4 index, 0..2303 (9*256)
            if (it < 4 || idx < 2304) {
                const int plane = idx >> 8;     // 0..8 = c*3 + hh
                const int f4    = idx & 255;
                const int c     = plane / 3;
                const int hh    = plane - c * 3;
                const int w     = f4 >> 3;          // 0..31
                const int d4    = (f4 & 7) << 2;    // 0,4,...,28
                const float4 val = *(const float4*)(xg + ((c * H_ + (oh + hh)) * W_ + w) * D_ + d4);
                *(float4*)&slab[((c * 3 + hh) * 32 + w) * 32 + d4] = val;
            }
        }
    }
    __syncthreads();

    // ---- bases for BOTH kk: aligned b128 reads + readfirstlane -> SGPRs ----
    int sA[2][16], sB[2][16];
    #pragma unroll
    for (int kk = 0; kk < 2; ++kk) {
        #pragma unroll
        for (int i = 0; i < 4; ++i) {
            const int4 qa = *(const int4*)&s_lb[kk][i * 4];
            sA[kk][i * 4 + 0] = __builtin_amdgcn_readfirstlane(qa.x);
            sA[kk][i * 4 + 1] = __builtin_amdgcn_readfirstlane(qa.y);
            sA[kk][i * 4 + 2] = __builtin_amdgcn_readfirstlane(qa.z);
            sA[kk][i * 4 + 3] = __builtin_amdgcn_readfirstlane(qa.w);
            const int4 qb = *(const int4*)&s_gb[kk][i * 4];
            sB[kk][i * 4 + 0] = __builtin_amdgcn_readfirstlane(qb.x);
            sB[kk][i * 4 + 1] = __builtin_amdgcn_readfirstlane(qb.y);
            sB[kk][i * 4 + 2] = __builtin_amdgcn_readfirstlane(qb.z);
            sB[kk][i * 4 + 3] = __builtin_amdgcn_readfirstlane(qb.w);
        }
    }

    // thread -> (column = tid>>5 [2 columns per wave], lane = od)
    const int odr = tid & 31;                // raw od lane, 0..31
    const int odc = min(odr, 29);            // clamped gather lane (30,31 dup 29)
    const int col = tid >> 5;                // 0..15

    #pragma unroll
    for (int p = 0; p < 2; ++p) {
        const int ow = col + p * 16;         // 0..31; wave-uniform validity:
        if (ow < 30) {                       //  wave 7 of pass 1 (ow 30,31) idles whole
            const int lt = ow * 32 + odc;    // shared lane term (dwords) for A and B

            #pragma unroll
            for (int kk = 0; kk < 2; ++kk) {
                // ---- fused levels 0+1: leaf pair -> level-1 node ----
                float v1[8];
                #pragma unroll
                for (int j = 0; j < 8; ++j) {
                    const int s0 = 2 * j, s1 = 2 * j + 1;
                    const float a0 = slab[sA[kk][s0] + lt];
                    const float b0 = xg[sB[kk][s0] + lt];
                    const float4 L0 = s_lut[kk][s0];
                    const float t0 = lut1(a0, b0, L0.x, L0.y, L0.z, L0.w);
                    const float a1 = slab[sA[kk][s1] + lt];
                    const float b1 = xg[sB[kk][s1] + lt];
                    const float4 L1 = s_lut[kk][s1];
                    const float t1 = lut1(a1, b1, L1.x, L1.y, L1.z, L1.w);
                    const float4 LN = s_lut[kk][16 + j];
                    v1[j] = lut1(t0, t1, LN.x, LN.y, LN.z, LN.w);
                }

                // ---- levels 2..4: widths 4,2,1 at node offsets 24,28,30 ----
                #pragma unroll
                for (int j = 0; j < 4; ++j) {
                    const float4 L = s_lut[kk][24 + j];
                    v1[j] = lut1(v1[2 * j], v1[2 * j + 1], L.x, L.y, L.z, L.w);
                }
                #pragma unroll
                for (int j = 0; j < 2; ++j) {
                    const float4 L = s_lut[kk][28 + j];
                    v1[j] = lut1(v1[2 * j], v1[2 * j + 1], L.x, L.y, L.z, L.w);
                }
                const float4 LT = s_lut[kk][30];
                const float r = lut1(v1[0], v1[1], LT.x, LT.y, LT.z, LT.w);

                // store one dword (lanes od 0..29; 30,31 masked)
                if (odr < 30) {
                    const int bk = b * K_ + k0 + kk;
                    out[(size_t)bk * 27000 + oh * 900 + ow * 30 + odr] = r;
                }
            }
        }
    }
}

extern "C" void kernel_launch(void* const* d_in, const int* in_sizes, int n_in,
                              void* d_out, int out_size, void* d_ws, size_t ws_size,
                              hipStream_t stream) {
    const float* x  = (const float*)d_in[0];
    const int*   kc = (const int*)d_in[1];
    const float* w0 = (const float*)d_in[2];
    const float* w1 = (const float*)d_in[3];
    const float* w2 = (const float*)d_in[4];
    const float* w3 = (const float*)d_in[5];
    const float* w4 = (const float*)d_in[6];
    float* out = (float*)d_out;

    dim3 grid(B_ * K_ / 2, 30);  // (b*16 + k-pair, oh) = 1920 blocks, 512 threads
    logic_conv3d<<<grid, TPB, 0, stream>>>(x, kc, w0, w1, w2, w3, w4, out);
}

// Round 9
// 80.814 us; speedup vs baseline: 1.1429x; 1.1429x over previous
//
#include <hip/hip_runtime.h>

// LogicConv3d: B=4, C=3, H=W=D=32, K=32, S=16 leaves, tree depth 4 (31 LUT nodes).
// Out: (B, K, 30, 30, 30) = 3,456,000 fp32.
//
// R19: restore of R14 (best measured: 82.02us), after R18's od-per-lane remap
// regressed (92.4us; kernel ~25.4 -> ~35.4us). Final lever scoreboard:
//   pipe choice (R5/R9/R10/R15): neutral, all-LDS +20% | occupancy 12->32
//   waves/CU (R11/R17/R18): <=-7% then flat | staging/barriers -50% (R13): -2%
//   SW pipeline (R14): 0% | VGPR 128->85 (R17): 0% | width 8->4->1: 0%/-40%.
// Redistributions are neutral; volume increases regress proportionally =>
// structural floor: 32 gathered leaf-reads (128B LDS+L1 traffic) + 93 FMA per
// output, un-hideable gather latency + issue overhead. ~25us kernel ~= 2x the
// naive pipe-sum; no remaining unfalsified mechanism.
//
// R14: explicit software pipeline over R13's structure: 512 thr, 4 oh-rows,
// slab 3c x 6h x 32 x 33 dw (76,032B, 2 blocks/CU), k-pair per block,
// A-leaves LDS / B-leaves global split, fused levels 0+1, bases via
// readfirstlane -> SGPRs, distance-1 operand prefetch through the 16-stage
// (2 kk x 8 j) leaf-pair stream.

#define B_  4
#define C_  3
#define H_  32
#define W_  32
#define D_  32
#define K_  32
#define S_  16
#define WS  33      // padded d-row stride (dwords); %32==1 rotates banks per ow
#define TPB 512

typedef float v8f __attribute__((ext_vector_type(8), aligned(4)));

__device__ __forceinline__ v8f lut8(v8f a, v8f b, float l0, float d1, float d2, float d3) {
    // E = l0 + a*d2 + b*d1 + (a*b)*d3 == fma(b, fma(a,d3,d1), fma(a,d2,l0))
    const v8f t0 = a * d2 + l0;
    const v8f t1 = a * d3 + d1;
    return b * t1 + t0;
}

__global__ __launch_bounds__(TPB, 4) void logic_conv3d(
    const float* __restrict__ x,
    const int*   __restrict__ kc,
    const float* __restrict__ w0,
    const float* __restrict__ w1,
    const float* __restrict__ w2,
    const float* __restrict__ w3,
    const float* __restrict__ w4,
    float*       __restrict__ out)
{
    __shared__ float4 s_lut[2][31];              // (l0, d1, d2, d3) per node, per kk
    __shared__ __align__(16) int s_lb[2][16];    // A-leaf base, slab coords, per kk
    __shared__ __align__(16) int s_gb[2][16];    // B-leaf base, global dword coords, per kk
    __shared__ __align__(16) float slab[18 * 32 * WS];  // 19008 dwords = 76032 B

    const int bx  = blockIdx.x;      // b*16 + kp
    const int b   = bx >> 4;
    const int k0  = (bx & 15) << 1;  // first k of this block's pair
    const int tid = threadIdx.x;
    const int oh0 = blockIdx.y * 4;  // first oh row of this block (0,4,...,28)

    // ---- per-block setup: 2 x (31 softmax->LUT delta form) + 2 x 32 leaf bases ----
    if (tid < 62) {
        const int kk   = (tid >= 31) ? 1 : 0;
        const int node = tid - kk * 31;
        const int k    = k0 + kk;
        const float* wp; int ln;
        if      (node < 16) { wp = w0; ln = node;      }
        else if (node < 24) { wp = w1; ln = node - 16; }
        else if (node < 28) { wp = w2; ln = node - 24; }
        else if (node < 30) { wp = w3; ln = node - 28; }
        else                { wp = w4; ln = 0;         }
        const float* wrow = wp + (ln * K_ + k) * 16;
        float lg[16];
        float m = -1e30f;
        #pragma unroll
        for (int g = 0; g < 16; ++g) { lg[g] = wrow[g]; m = fmaxf(m, lg[g]); }
        float z = 0.f;
        #pragma unroll
        for (int g = 0; g < 16; ++g) { lg[g] = __expf(lg[g] - m); z += lg[g]; }
        const float inv = 1.0f / z;
        float l0 = 0.f, l1 = 0.f, l2 = 0.f, l3 = 0.f;
        #pragma unroll
        for (int g = 0; g < 16; ++g) {
            float p = lg[g] * inv;           // GATES[g,t] = (g>>t)&1, t = 2*a+b
            if (g & 1) l0 += p;
            if (g & 2) l1 += p;
            if (g & 4) l2 += p;
            if (g & 8) l3 += p;
        }
        s_lut[kk][node] = make_float4(l0, l1 - l0, l2 - l0, (l3 - l2) - (l1 - l0));
    } else if (tid >= 64 && tid < 128) {
        const int idx  = tid - 64;           // kk*32 + tree*16 + s
        const int kk   = idx >> 5;
        const int tree = (idx >> 4) & 1;
        const int s    = idx & 15;
        const int k    = k0 + kk;
        const int off  = ((tree * K_ + k) * S_ + s) * 4;  // kc (2,K,S,4) = (h,w,d,c)
        const int h = kc[off + 0], w = kc[off + 1], d = kc[off + 2], c = kc[off + 3];
        if (tree == 0)
            s_lb[kk][s] = ((c * 6 + h) * 32 + w) * WS + d;    // slab coords (6 h-rows)
        else
            s_gb[kk][s] = ((c * H_ + h) * W_ + w) * D_ + d;   // global coords
    }

    // ---- stage slab: 18 planes (3c x 6h) of 32x32 dwords, coalesced float4 ----
    {
        const float* xb = x + (size_t)b * (C_ * H_ * W_ * D_);
        #pragma unroll
        for (int it = 0; it < 9; ++it) {
            const int idx   = it * TPB + tid;   // float4 index, 0..4607 (18*256)
            const int plane = idx >> 8;         // 0..17 = c*6 + dh
            const int f4    = idx & 255;
            const int c     = plane / 6;
            const int dh    = plane - c * 6;
            const int h     = min(oh0 + dh, H_ - 1);   // clamp for y=7 tail (values unused)
            const int w     = f4 >> 3;          // 0..31
            const int d4    = (f4 & 7) << 2;    // 0,4,...,28
            const float4 val = *(const float4*)(xb + ((c * H_ + h) * W_ + w) * D_ + d4);
            *(float4*)&slab[(plane * 32 + w) * WS + d4] = val;
        }
    }
    __syncthreads();

    // ---- bases for BOTH kk: aligned b128 reads + readfirstlane -> SGPRs ----
    int sA[2][16], sB[2][16];
    #pragma unroll
    for (int kk = 0; kk < 2; ++kk) {
        #pragma unroll
        for (int i = 0; i < 4; ++i) {
            const int4 qa = *(const int4*)&s_lb[kk][i * 4];
            sA[kk][i * 4 + 0] = __builtin_amdgcn_readfirstlane(qa.x);
            sA[kk][i * 4 + 1] = __builtin_amdgcn_readfirstlane(qa.y);
            sA[kk][i * 4 + 2] = __builtin_amdgcn_readfirstlane(qa.z);
            sA[kk][i * 4 + 3] = __builtin_amdgcn_readfirstlane(qa.w);
            const int4 qb = *(const int4*)&s_gb[kk][i * 4];
            sB[kk][i * 4 + 0] = __builtin_amdgcn_readfirstlane(qb.x);
            sB[kk][i * 4 + 1] = __builtin_amdgcn_readfirstlane(qb.y);
            sB[kk][i * 4 + 2] = __builtin_amdgcn_readfirstlane(qb.z);
            sB[kk][i * 4 + 3] = __builtin_amdgcn_readfirstlane(qb.w);
        }
    }

    // thread -> (oh_local 0..3, ow, octet of consecutive od)
    const int ohl = tid >> 7;                // 0..3
    const int r   = tid & 127;
    const int ow  = r >> 2;                  // 0..31 (>=30 inactive)
    const int gq  = r & 3;                   // 0..3
    const int od0 = (gq < 3) ? (gq << 3) : 22;  // 0,8,16,22; gq=3 overlaps gq=2 by 2
    const int oh  = oh0 + ohl;

    if (ow < 30 && oh < 30) {
        const int vo  = ohl * (32 * WS) + ow * WS + od0;            // slab offset (A)
        const int gvo = ohl * (W_ * D_) + ow * D_ + od0;            // global offset (B)
        const float* xg = x + (size_t)b * (C_ * H_ * W_ * D_) + oh0 * (W_ * D_);

        #define LD_A(kk, s) (*(const v8f*)&slab[sA[kk][s] + vo])
        #define LD_B(kk, s) (*(const v8f*)(xg + sB[kk][s] + gvo))

        // ---- software-pipelined 16-stage leaf-pair stream (2 kk x 8 j) ----
        // prologue: stage (kk=0, j=0)
        v8f cA0 = LD_A(0, 0), cB0 = LD_B(0, 0);
        v8f cA1 = LD_A(0, 1), cB1 = LD_B(0, 1);

        v8f v1[8];
        #pragma unroll
        for (int kk = 0; kk < 2; ++kk) {
            #pragma unroll
            for (int j = 0; j < 8; ++j) {
                // issue next stage's loads BEFORE this stage's 72 FMAs
                const int nkk = (j == 7) ? kk + 1 : kk;
                const int nj  = (j == 7) ? 0 : j + 1;
                v8f nA0 = cA0, nB0 = cB0, nA1 = cA1, nB1 = cB1;
                if (nkk < 2) {
                    nB0 = LD_B(nkk, 2 * nj);
                    nB1 = LD_B(nkk, 2 * nj + 1);
                    nA0 = LD_A(nkk, 2 * nj);
                    nA1 = LD_A(nkk, 2 * nj + 1);
                }
                // fused levels 0+1: leaf pair -> level-1 node
                const float4 L0 = s_lut[kk][2 * j];
                const v8f t0 = lut8(cA0, cB0, L0.x, L0.y, L0.z, L0.w);
                const float4 L1 = s_lut[kk][2 * j + 1];
                const v8f t1 = lut8(cA1, cB1, L1.x, L1.y, L1.z, L1.w);
                const float4 LN = s_lut[kk][16 + j];
                v1[j] = lut8(t0, t1, LN.x, LN.y, LN.z, LN.w);
                cA0 = nA0; cB0 = nB0; cA1 = nA1; cB1 = nB1;
            }

            // ---- levels 2..4: widths 4,2,1 at node offsets 24,28,30 ----
            // (kk=1 j0 operands prefetched above ride out this tail)
            v8f v2[4];
            #pragma unroll
            for (int j = 0; j < 4; ++j) {
                const float4 L = s_lut[kk][24 + j];
                v2[j] = lut8(v1[2 * j], v1[2 * j + 1], L.x, L.y, L.z, L.w);
            }
            v8f v3[2];
            #pragma unroll
            for (int j = 0; j < 2; ++j) {
                const float4 L = s_lut[kk][28 + j];
                v3[j] = lut8(v2[2 * j], v2[2 * j + 1], L.x, L.y, L.z, L.w);
            }
            v8f v4;
            {
                const float4 L = s_lut[kk][30];
                v4 = lut8(v3[0], v3[1], L.x, L.y, L.z, L.w);
            }

            // store 8 consecutive od (gq=3 overlaps gq=2 with identical values)
            const int bk = b * K_ + k0 + kk;
            float* outp = out + (size_t)bk * 27000 + oh * 900 + ow * 30 + od0;
            *(v8f*)outp = v4;
        }
        #undef LD_A
        #undef LD_B
    }
}

extern "C" void kernel_launch(void* const* d_in, const int* in_sizes, int n_in,
                              void* d_out, int out_size, void* d_ws, size_t ws_size,
                              hipStream_t stream) {
    const float* x  = (const float*)d_in[0];
    const int*   kc = (const int*)d_in[1];
    const float* w0 = (const float*)d_in[2];
    const float* w1 = (const float*)d_in[3];
    const float* w2 = (const float*)d_in[4];
    const float* w3 = (const float*)d_in[5];
    const float* w4 = (const float*)d_in[6];
    float* out = (float*)d_out;

    dim3 grid((B_ * K_) / 2, 8);  // (b*16 + k-pair, oh-quad) = 512 blocks, 512 threads
    logic_conv3d<<<grid, TPB, 0, stream>>>(x, kc, w0, w1, w2, w3, w4, out);
}